// Round 17
// baseline (462.998 us; speedup 1.0000x reference)
//
#include <hip/hip_runtime.h>
#include <cstdio>

#define NB 40
#define NS 8
#define NT 441
#define DIN 768
#define DD 128
#define NTOT (NB*NT)
#define FSCALE 0.08838834764831843f

typedef short s8v __attribute__((ext_vector_type(8)));
typedef float f4v __attribute__((ext_vector_type(4)));

__device__ inline ushort f2bf(float f){
  unsigned u = __float_as_uint(f);
  unsigned r = (u + 0x7fffu + ((u >> 16) & 1u)) >> 16;
  return (ushort)r;
}
__device__ inline float bf2f(ushort h){ return __uint_as_float(((unsigned)h) << 16); }

struct PP {
  const float *inputs; const int *tok_idx; const float *abs_grid;
  const float *slots_init, *Sp_init, *Ss_init;
  const float *WQ, *ln_g, *ln_b;
  const float *gru_w_ih, *gru_w_hh, *gru_b_ih, *gru_b_hh;
  const float *mlp_ln_g, *mlp_ln_b, *mlp_w1, *mlp_b1, *mlp_w2, *mlp_b2;
  const float *WK, *WV, *Wg, *bg, *Wf1, *bf1, *Wf2, *bf2;
  const float *im_ln1_g, *im_ln1_b, *im_w1, *im_b1, *im_w2, *im_b2, *im_ln2_g, *im_ln2_b;
  const float *fin_w, *fin_b;
  float *A_K, *A_V, *Wg1, *c1, *Wf2T;
  float *slots_g, *qw_g, *qb_g, *spss_g, *hpart_g, *a_g;
  ushort *xnh, *xnl, *hh, *hl, *W1Th, *W1Tl, *W2Th, *W2Tl;
  ushort *WKfTh, *WKfTl, *WVfTh, *WVfTl;
  float *out;
};

// ---------- weight prep ----------
__global__ __launch_bounds__(128) void prep_weights(PP p){
  int r = blockIdx.x, d = threadIdx.x;
  float accK = 0.f, accV = 0.f;
  for (int kk = 0; kk < DD; kk++){
    float w = p.Wf1[kk*DD + d];
    accK = fmaf(p.WK[r*DD+kk], w, accK);
    accV = fmaf(p.WV[r*DD+kk], w, accV);
  }
  ushort hk = f2bf(accK), hv = f2bf(accV);
  p.WKfTh[d*DD + r] = hk; p.WKfTl[d*DD + r] = f2bf(accK - bf2f(hk));
  p.WVfTh[d*DD + r] = hv; p.WVfTl[d*DD + r] = f2bf(accV - bf2f(hv));
  if (r < 2){
    float a = 0.f;
    for (int kk = 0; kk < DD; kk++) a = fmaf(p.Wg[r*DD+kk], p.Wf1[kk*DD+d], a);
    p.Wg1[r*DD+d] = a;
  }
  if (r == 2){
    float a = 0.f;
    for (int kk = 0; kk < DD; kk++) a = fmaf(p.bg[kk], p.Wf1[kk*DD+d], a);
    p.c1[d] = a + p.bf1[d];
  }
  p.Wf2T[d*DD + r] = p.Wf2[r*DD + d];
}

// ---------- combined transpose + bf16 split for im_w1 and im_w2 ----------
__global__ __launch_bounds__(256) void transpose_both(PP p){
  __shared__ float tile[64][65];
  int t = blockIdx.x;
  const float* W; ushort *WTh, *WTl; int N, k0, n0;
  if (t < 144){ W = p.im_w1; WTh = p.W1Th; WTl = p.W1Tl; N = 768; k0 = (t/12)*64; n0 = (t%12)*64; }
  else { t -= 144; W = p.im_w2; WTh = p.W2Th; WTl = p.W2Tl; N = 128; k0 = (t/2)*64; n0 = (t&1)*64; }
  int tid = threadIdx.x;
  #pragma unroll
  for (int i = 0; i < 4; i++){
    int k = i*16 + (tid >> 4);
    int n4 = (tid & 15) * 4;
    float4 v = *(const float4*)(W + (long)(k0+k)*N + n0 + n4);
    tile[k][n4+0] = v.x; tile[k][n4+1] = v.y; tile[k][n4+2] = v.z; tile[k][n4+3] = v.w;
  }
  __syncthreads();
  #pragma unroll
  for (int i = 0; i < 4; i++){
    int n = i*16 + (tid >> 4);
    int k4 = (tid & 15) * 4;
    ushort4 h4, l4;
    float v0 = tile[k4+0][n], v1 = tile[k4+1][n], v2 = tile[k4+2][n], v3 = tile[k4+3][n];
    h4.x = f2bf(v0); l4.x = f2bf(v0 - bf2f(h4.x));
    h4.y = f2bf(v1); l4.y = f2bf(v1 - bf2f(h4.y));
    h4.z = f2bf(v2); l4.z = f2bf(v2 - bf2f(h4.z));
    h4.w = f2bf(v3); l4.w = f2bf(v3 - bf2f(h4.w));
    *(ushort4*)(WTh + (long)(n0+n)*DIN + k0 + k4) = h4;
    *(ushort4*)(WTl + (long)(n0+n)*DIN + k0 + k4) = l4;
  }
}

// ---------- phase0 ----------
__device__ void phase0g(const PP& p, int bs, int tid, float* scr, const float* sl,
                        float Sp0, float Sp1, float Ss0, float Ss1){
  float* sn   = scr;
  float* qv   = scr + 128;
  float* part = scr + 256;
  float* red  = scr + 512;
  int o = tid & 127, h = tid >> 7;
  float v = (tid < 128) ? sl[tid] : 0.f;
  float s1 = v, s2 = v*v;
  #pragma unroll
  for (int m = 1; m < 64; m <<= 1){ s1 += __shfl_xor(s1,m); s2 += __shfl_xor(s2,m); }
  if (tid < 128 && (tid & 63) == 0){ red[(tid>>6)*2] = s1; red[(tid>>6)*2+1] = s2; }
  __syncthreads();
  float mean = (red[0]+red[2])*(1.f/128.f);
  float var  = (red[1]+red[3])*(1.f/128.f) - mean*mean;
  float rstd = rsqrtf(var + 1e-5f);
  if (tid < 128) sn[tid] = (v-mean)*rstd*p.ln_g[tid] + p.ln_b[tid];
  __syncthreads();
  float acc = 0.f;
  #pragma unroll 4
  for (int k = 0; k < 64; k++) acc = fmaf(sn[h*64+k], p.WQ[(h*64+k)*128+o], acc);
  part[h*128+o] = acc;
  __syncthreads();
  if (tid < 128) qv[tid] = part[tid] + part[128+tid];
  __syncthreads();
  float acc2 = 0.f;
  #pragma unroll 4
  for (int k = 0; k < 64; k++) acc2 = fmaf(qv[h*64+k], p.Wf2T[(h*64+k)*128+o], acc2);
  part[h*128+o] = acc2;
  __syncthreads();
  if (tid < 128) p.qw_g[(long)bs*128+tid] = part[tid] + part[128+tid];
  float pb = (tid < 128) ? qv[tid]*p.bf2[tid] : 0.f;
  #pragma unroll
  for (int m = 1; m < 64; m <<= 1) pb += __shfl_xor(pb,m);
  if ((tid & 63) == 0) red[4 + (tid>>6)] = pb;
  __syncthreads();
  if (tid == 0){
    p.qb_g[bs] = FSCALE*(red[4]+red[5]+red[6]+red[7]);
    p.spss_g[bs*4+0] = Sp0; p.spss_g[bs*4+1] = Sp1;
    p.spss_g[bs*4+2] = 1.f/(Ss0*5.0f); p.spss_g[bs*4+3] = 1.f/(Ss1*5.0f);
  }
}

// ---------- LN1+split (blocks 0..4409) and slot init (blocks 4410..4729) ----------
__global__ __launch_bounds__(256) void ln1_init(PP p){
  __shared__ float sl[128];
  __shared__ float scr[520];
  if (blockIdx.x < 4410){
    int tok = blockIdx.x*4 + (threadIdx.x >> 6);
    int l = threadIdx.x & 63;
    const float* src = p.inputs + (long)tok*DIN;
    float4 v[3];
    float s = 0.f, s2 = 0.f;
    #pragma unroll
    for (int pp = 0; pp < 3; pp++){
      v[pp] = *(const float4*)(src + pp*256 + l*4);
      s  += v[pp].x + v[pp].y + v[pp].z + v[pp].w;
      s2 += v[pp].x*v[pp].x + v[pp].y*v[pp].y + v[pp].z*v[pp].z + v[pp].w*v[pp].w;
    }
    #pragma unroll
    for (int m = 1; m < 64; m <<= 1){ s += __shfl_xor(s, m); s2 += __shfl_xor(s2, m); }
    float mean = s*(1.f/DIN), var = s2*(1.f/DIN) - mean*mean;
    float rstd = rsqrtf(var + 1e-5f);
    #pragma unroll
    for (int pp = 0; pp < 3; pp++){
      int idx = pp*256 + l*4;
      float4 g = *(const float4*)(p.im_ln1_g + idx);
      float4 b = *(const float4*)(p.im_ln1_b + idx);
      float y0 = (v[pp].x-mean)*rstd*g.x + b.x;
      float y1 = (v[pp].y-mean)*rstd*g.y + b.y;
      float y2 = (v[pp].z-mean)*rstd*g.z + b.z;
      float y3 = (v[pp].w-mean)*rstd*g.w + b.w;
      ushort4 h4, l4;
      h4.x = f2bf(y0); l4.x = f2bf(y0 - bf2f(h4.x));
      h4.y = f2bf(y1); l4.y = f2bf(y1 - bf2f(h4.y));
      h4.z = f2bf(y2); l4.z = f2bf(y2 - bf2f(h4.z));
      h4.w = f2bf(y3); l4.w = f2bf(y3 - bf2f(h4.w));
      *(ushort4*)(p.xnh + (long)tok*DIN + idx) = h4;
      *(ushort4*)(p.xnl + (long)tok*DIN + idx) = l4;
    }
  } else {
    int bs = blockIdx.x - 4410, ss = bs & 7, tid = threadIdx.x;
    if (tid < 128){
      float v = p.slots_init[ss*128+tid];
      sl[tid] = v;
      p.slots_g[(long)bs*128+tid] = v;
    }
    __syncthreads();
    phase0g(p, bs, tid, scr, sl,
            p.Sp_init[ss*2], p.Sp_init[ss*2+1], p.Ss_init[ss*2], p.Ss_init[ss*2+1]);
  }
}

// ---------- GEMM1: 128x128, XCD m-grouping, swizzled global_load_lds, 2-phase dbuf ----------
__global__ __launch_bounds__(256, 2) void gemm1_128(PP p){
  __shared__ __align__(16) ushort LDSm[32768];
  int id = blockIdx.x;
  int xcd = id & 7, idx = id >> 3;
  int m_t = xcd + 8*(idx/6), n_t = idx % 6;
  if (m_t >= 138) return;
  int m0 = m_t*128, n0 = n_t*128;
  int tid = threadIdx.x;
  int w = tid >> 6, lane = tid & 63;
  int wm = w >> 1, wn = w & 1;
  int lch = lane ^ ((lane >> 3) & 7);
  int r_in = lch >> 2, kgs = lch & 3;
  const ushort* S = (w == 0) ? p.xnh : (w == 1) ? p.xnl : (w == 2) ? p.W1Th : p.W1Tl;
  int base0 = (w < 2) ? m0 : n0;
  bool isA = (w < 2);
  int kg = lane >> 4, rA = lane & 15;
  int cc = rA*4 + kg;
  int cs = cc ^ ((cc >> 3) & 7);
  const char* LB = (const char*)LDSm;

  f4v acc[4][4];
  #pragma unroll
  for (int mf = 0; mf < 4; mf++)
    #pragma unroll
    for (int nf = 0; nf < 4; nf++) acc[mf][nf] = (f4v)(0.f);

  #pragma unroll
  for (int t = 0; t < 8; t++){
    int grow = base0 + t*16 + r_in;
    if (isA) grow = min(grow, NTOT-1);
    const ushort* gptr = S + (long)grow*DIN + 0 + kgs*8;
    ushort* lptr = &LDSm[w*4096 + t*512];
    __builtin_amdgcn_global_load_lds(
        (const __attribute__((address_space(1))) void*)gptr,
        (__attribute__((address_space(3))) void*)lptr, 16, 0, 0);
  }
  __syncthreads();

  int cur = 0;
  for (int kb = 0; kb < DIN; kb += 32){
    if (kb + 32 < DIN){
      int nb = cur ^ 1;
      #pragma unroll
      for (int t = 0; t < 8; t++){
        int grow = base0 + t*16 + r_in;
        if (isA) grow = min(grow, NTOT-1);
        const ushort* gptr = S + (long)grow*DIN + (kb + 32) + kgs*8;
        ushort* lptr = &LDSm[nb*16384 + w*4096 + t*512];
        __builtin_amdgcn_global_load_lds(
            (const __attribute__((address_space(1))) void*)gptr,
            (__attribute__((address_space(3))) void*)lptr, 16, 0, 0);
      }
    }
    const char* B = LB + cur*32768;
    s8v a0[4], a1[4], b0[4], b1[4];
    #pragma unroll
    for (int mf = 0; mf < 4; mf++){
      int win = wm*4 + mf;
      a0[mf] = *(const s8v*)(B +         win*1024 + cs*16);
      a1[mf] = *(const s8v*)(B +  8192 + win*1024 + cs*16);
    }
    #pragma unroll
    for (int nf = 0; nf < 4; nf++){
      int win = wn*4 + nf;
      b0[nf] = *(const s8v*)(B + 16384 + win*1024 + cs*16);
      b1[nf] = *(const s8v*)(B + 24576 + win*1024 + cs*16);
    }
    #pragma unroll
    for (int mf = 0; mf < 4; mf++)
      #pragma unroll
      for (int nf = 0; nf < 4; nf++){
        acc[mf][nf] = __builtin_amdgcn_mfma_f32_16x16x32_bf16(a0[mf], b0[nf], acc[mf][nf], 0, 0, 0);
        acc[mf][nf] = __builtin_amdgcn_mfma_f32_16x16x32_bf16(a0[mf], b1[nf], acc[mf][nf], 0, 0, 0);
        acc[mf][nf] = __builtin_amdgcn_mfma_f32_16x16x32_bf16(a1[mf], b0[nf], acc[mf][nf], 0, 0, 0);
      }
    __syncthreads();
    cur ^= 1;
  }

  int rbase = (lane >> 4) * 4, cn = lane & 15;
  #pragma unroll
  for (int mf = 0; mf < 4; mf++)
    #pragma unroll
    for (int nf = 0; nf < 4; nf++){
      int n = n0 + wn*64 + nf*16 + cn;
      float bs = p.im_b1[n];
      #pragma unroll
      for (int r = 0; r < 4; r++){
        int m = m0 + wm*64 + mf*16 + rbase + r;
        if (m < NTOT){
          float v = fmaxf(acc[mf][nf][r] + bs, 0.f);
          ushort h = f2bf(v);
          p.hh[(long)m*DIN + n] = h;
          p.hl[(long)m*DIN + n] = f2bf(v - bf2f(h));
        }
      }
    }
}

// ---------- GEMM2 fused, BM=32 ----------
__global__ __launch_bounds__(256) void gemm2_fused(PP p){
  __shared__ __align__(16) char smem[43008];
  ushort* As = (ushort*)smem;
  ushort* Bs = (ushort*)(smem + 5120);
  float*  Dl = (float*)smem;
  ushort* xsh = (ushort*)(smem + 25600);
  ushort* xsl = (ushort*)(smem + 25600 + 8704);
  int m0 = blockIdx.x * 32;
  int tid = threadIdx.x, w = tid >> 6, lane = tid & 63;
  f4v acc[2][2];
  #pragma unroll
  for (int mf = 0; mf < 2; mf++)
    #pragma unroll
    for (int nf = 0; nf < 2; nf++) acc[mf][nf] = (f4v)(0.f);

  for (int kb = 0; kb < DIN; kb += 32){
    __syncthreads();
    {
      int c = tid;
      int s = c >> 7, rem = c & 127, r = rem >> 2, kg = rem & 3;
      int gr = min(m0 + r, NTOT-1);
      const float4 va = *(const float4*)((s ? p.hl : p.hh) + (long)gr*DIN + kb + kg*8);
      *(float4*)(As + s*1280 + r*40 + kg*8) = va;
    }
    #pragma unroll
    for (int i = 0; i < 4; i++){
      int c = tid + i*256;
      int s = c >> 9, r = (c >> 2) & 127, kg = c & 3;
      const float4 vb = *(const float4*)((s ? p.W2Tl : p.W2Th) + (long)r*DIN + kb + kg*8);
      *(float4*)(Bs + s*5120 + r*40 + kg*8) = vb;
    }
    __syncthreads();
    int kg = lane >> 4, rA = lane & 15;
    s8v a0[2], a1[2], b0[2], b1[2];
    #pragma unroll
    for (int mf = 0; mf < 2; mf++){
      a0[mf] = *(const s8v*)(As +        (mf*16 + rA)*40 + kg*8);
      a1[mf] = *(const s8v*)(As + 1280 + (mf*16 + rA)*40 + kg*8);
    }
    #pragma unroll
    for (int nf = 0; nf < 2; nf++){
      int rb = w*32 + nf*16 + rA;
      b0[nf] = *(const s8v*)(Bs +        rb*40 + kg*8);
      b1[nf] = *(const s8v*)(Bs + 5120 + rb*40 + kg*8);
    }
    #pragma unroll
    for (int mf = 0; mf < 2; mf++)
      #pragma unroll
      for (int nf = 0; nf < 2; nf++){
        acc[mf][nf] = __builtin_amdgcn_mfma_f32_16x16x32_bf16(a0[mf], b0[nf], acc[mf][nf], 0, 0, 0);
        acc[mf][nf] = __builtin_amdgcn_mfma_f32_16x16x32_bf16(a0[mf], b1[nf], acc[mf][nf], 0, 0, 0);
        acc[mf][nf] = __builtin_amdgcn_mfma_f32_16x16x32_bf16(a1[mf], b0[nf], acc[mf][nf], 0, 0, 0);
      }
  }

  int rbase = (lane >> 4) * 4, cn = lane & 15;
  __syncthreads();
  #pragma unroll
  for (int mf = 0; mf < 2; mf++)
    #pragma unroll
    for (int nf = 0; nf < 2; nf++){
      int n = w*32 + nf*16 + cn;
      float bs = p.im_b2[n];
      #pragma unroll
      for (int r = 0; r < 4; r++)
        Dl[(mf*16 + rbase + r)*132 + n] = acc[mf][nf][r] + bs;
    }
  __syncthreads();
  for (int rr = 0; rr < 8; rr++){
    int row = w*8 + rr;
    float e0 = Dl[row*132 + lane], e1 = Dl[row*132 + 64 + lane];
    float s = e0 + e1, s2 = e0*e0 + e1*e1;
    #pragma unroll
    for (int m2 = 1; m2 < 64; m2 <<= 1){ s += __shfl_xor(s, m2); s2 += __shfl_xor(s2, m2); }
    float mean = s*(1.f/DD), var = s2*(1.f/DD) - mean*mean;
    float rstd = rsqrtf(var + 1e-5f);
    float x0 = (e0-mean)*rstd*p.im_ln2_g[lane]    + p.im_ln2_b[lane];
    float x1 = (e1-mean)*rstd*p.im_ln2_g[64+lane] + p.im_ln2_b[64+lane];
    ushort h0 = f2bf(x0), h1 = f2bf(x1);
    xsh[row*136 + lane]      = h0;  xsl[row*136 + lane]      = f2bf(x0 - bf2f(h0));
    xsh[row*136 + 64 + lane] = h1;  xsl[row*136 + 64 + lane] = f2bf(x1 - bf2f(h1));
  }
  __syncthreads();
  int kg = lane >> 4, rA = lane & 15;
  int kv = w >> 1, rowblk = w & 1;
  const ushort* WTh = kv ? p.WVfTh : p.WKfTh;
  const ushort* WTl = kv ? p.WVfTl : p.WKfTl;
  float* OUT = kv ? p.A_V : p.A_K;
  f4v aO[8];
  #pragma unroll
  for (int nf = 0; nf < 8; nf++) aO[nf] = (f4v)(0.f);
  #pragma unroll
  for (int kb2 = 0; kb2 < 4; kb2++){
    s8v ah = *(const s8v*)&xsh[(rowblk*16+rA)*136 + kb2*32 + kg*8];
    s8v al = *(const s8v*)&xsl[(rowblk*16+rA)*136 + kb2*32 + kg*8];
    #pragma unroll
    for (int nf = 0; nf < 8; nf++){
      int n = nf*16 + rA;
      s8v bh = *(const s8v*)(WTh + n*DD + kb2*32 + kg*8);
      s8v bl = *(const s8v*)(WTl + n*DD + kb2*32 + kg*8);
      aO[nf] = __builtin_amdgcn_mfma_f32_16x16x32_bf16(ah, bh, aO[nf], 0, 0, 0);
      aO[nf] = __builtin_amdgcn_mfma_f32_16x16x32_bf16(ah, bl, aO[nf], 0, 0, 0);
      aO[nf] = __builtin_amdgcn_mfma_f32_16x16x32_bf16(al, bh, aO[nf], 0, 0, 0);
    }
  }
  #pragma unroll
  for (int nf = 0; nf < 8; nf++){
    int n = nf*16 + cn;
    float c = p.c1[n];
    #pragma unroll
    for (int r = 0; r < 4; r++){
      int m = m0 + rowblk*16 + rbase + r;
      if (m < NTOT) OUT[(long)m*DD + n] = aO[nf][r] + c;
    }
  }
}

// ---------- kA ----------
template<int LAST>
__global__ __launch_bounds__(256) void kA(PP p){
  int b = blockIdx.x / 7, tile = blockIdx.x % 7;
  int tid = threadIdx.x, wid = tid >> 6, lane = tid & 63;
  __shared__ float qws[8][132];
  __shared__ float qbs[8];
  __shared__ float spssL[32];
  __shared__ float agt[64][2];
  __shared__ float a_tile[8][64];
  __shared__ float hpartL[4][8][128];
  for (int f = tid; f < 8*128; f += 256){
    int s = f >> 7, d = f & 127;
    qws[s][(d&31)*4 + (d>>5)] = p.qw_g[((long)b*8+s)*128 + d];
  }
  if (tid < 8)  qbs[tid] = p.qb_g[b*8+tid];
  if (tid < 32) spssL[tid] = p.spss_g[b*32+tid];
  if (tid < 64){
    int j = tile*64 + tid;
    float g0 = 0.f, g1 = 0.f;
    if (j < NT){ int idx = p.tok_idx[b*NT+j]; g0 = p.abs_grid[idx*2]; g1 = p.abs_grid[idx*2+1]; }
    agt[tid][0] = g0; agt[tid][1] = g1;
  }
  __syncthreads();

  {
    int tl = lane >> 2, dg = lane & 3;
    int jtok = wid*16 + tl, j = tile*64 + jtok;
    bool valid = j < NT;
    int jc = valid ? j : 0;
    float aa[32], w0[32], w1[32];
    const float* src = p.A_K + ((long)(b*NT+jc))*DD + dg*32;
    #pragma unroll
    for (int i4 = 0; i4 < 8; i4++){
      float4 t = *(const float4*)(src + i4*4);
      aa[i4*4+0]=t.x; aa[i4*4+1]=t.y; aa[i4*4+2]=t.z; aa[i4*4+3]=t.w;
    }
    #pragma unroll
    for (int i4 = 0; i4 < 8; i4++){
      float4 t0 = *(const float4*)(p.Wg1 + dg*32 + i4*4);
      float4 t1 = *(const float4*)(p.Wg1 + DD + dg*32 + i4*4);
      w0[i4*4+0]=t0.x; w0[i4*4+1]=t0.y; w0[i4*4+2]=t0.z; w0[i4*4+3]=t0.w;
      w1[i4*4+0]=t1.x; w1[i4*4+1]=t1.y; w1[i4*4+2]=t1.z; w1[i4*4+3]=t1.w;
    }
    float ag0 = agt[jtok][0], ag1 = agt[jtok][1];
    float dv[8];
    #pragma unroll
    for (int s = 0; s < 8; s++){
      float rel0 = (ag0 - spssL[s*4+0])*spssL[s*4+2];
      float rel1 = (ag1 - spssL[s*4+1])*spssL[s*4+3];
      float acc = 0.f;
      #pragma unroll
      for (int i = 0; i < 32; i++){
        float hk = fmaxf(fmaf(rel0, w0[i], fmaf(rel1, w1[i], aa[i])), 0.f);
        acc = fmaf(hk, qws[s][i*4+dg], acc);
      }
      acc += __shfl_xor(acc, 1); acc += __shfl_xor(acc, 2);
      dv[s] = acc*FSCALE + qbs[s];
    }
    if (dg == 0){
      float m = -1e30f;
      #pragma unroll
      for (int s = 0; s < 8; s++) m = fmaxf(m, dv[s]);
      float tot = 0.f;
      #pragma unroll
      for (int s = 0; s < 8; s++){ dv[s] = expf(dv[s]-m); tot += dv[s]; }
      float inv = 1.f/tot;
      #pragma unroll
      for (int s = 0; s < 8; s++)
        a_tile[s][jtok] = valid ? (dv[s]*inv + 1e-8f) : 0.f;
    }
  }
  __syncthreads();

  #pragma unroll
  for (int si = 0; si < 2; si++){
    int s = wid*2 + si;
    float a = a_tile[s][lane];
    float g0 = agt[lane][0], g1 = agt[lane][1];
    float v0 = a, v1 = a*g0, v2 = a*g1, v3 = a*g0*g0, v4 = a*g1*g1;
    #pragma unroll
    for (int m = 1; m < 64; m <<= 1){
      v0 += __shfl_xor(v0,m); v1 += __shfl_xor(v1,m); v2 += __shfl_xor(v2,m);
      v3 += __shfl_xor(v3,m); v4 += __shfl_xor(v4,m);
    }
    if (lane == 0){
      float* st = p.hpart_g + ((long)(b*7+tile)*8 + s)*136 + 128;
      st[0]=v0; st[1]=v1; st[2]=v2; st[3]=v3; st[4]=v4;
    }
  }

  if (LAST){
    if ((b % 5) == 2){
      int clip = b/5;
      for (int f = tid; f < 8*64; f += 256){
        int s = f >> 6, jt = f & 63;
        int j = tile*64 + jt;
        if (j < NT) p.a_g[((long)clip*8 + s)*NT + j] = a_tile[s][jt];
      }
    }
    return;
  }

  {
    float sp0[8], sp1[8], si0[8], si1[8];
    #pragma unroll
    for (int s = 0; s < 8; s++){
      sp0[s]=spssL[s*4+0]; sp1[s]=spssL[s*4+1]; si0[s]=spssL[s*4+2]; si1[s]=spssL[s*4+3];
    }
    int d0 = lane, d1 = lane + 64;
    float wg0a = p.Wg1[d0], wg1a = p.Wg1[DD+d0];
    float wg0b = p.Wg1[d1], wg1b = p.Wg1[DD+d1];
    float acc0[8], acc1[8];
    #pragma unroll
    for (int s = 0; s < 8; s++){ acc0[s]=0.f; acc1[s]=0.f; }
    #pragma unroll 4
    for (int jj = wid; jj < 64; jj += 4){
      int j = tile*64 + jj;
      if (j >= NT) continue;
      float av0 = p.A_V[((long)(b*NT+j))*DD + d0];
      float av1 = p.A_V[((long)(b*NT+j))*DD + d1];
      float g0 = agt[jj][0], g1 = agt[jj][1];
      #pragma unroll
      for (int s = 0; s < 8; s++){
        float rel0 = (g0 - sp0[s])*si0[s];
        float rel1 = (g1 - sp1[s])*si1[s];
        float a = a_tile[s][jj];
        float hv0 = fmaxf(fmaf(rel0, wg0a, fmaf(rel1, wg1a, av0)), 0.f);
        float hv1 = fmaxf(fmaf(rel0, wg0b, fmaf(rel1, wg1b, av1)), 0.f);
        acc0[s] = fmaf(a, hv0, acc0[s]);
        acc1[s] = fmaf(a, hv1, acc1[s]);
      }
    }
    #pragma unroll
    for (int s = 0; s < 8; s++){ hpartL[wid][s][d0] = acc0[s]; hpartL[wid][s][d1] = acc1[s]; }
    __syncthreads();
    for (int f = tid; f < 1024; f += 256){
      int s = f >> 7, d = f & 127;
      p.hpart_g[((long)(b*7+tile)*8 + s)*136 + d] =
        hpartL[0][s][d] + hpartL[1][s][d] + hpartL[2][s][d] + hpartL[3][s][d];
    }
  }
}

// ---------- kB ----------
template<int LAST>
__global__ __launch_bounds__(256) void kB(PP p){
  __shared__ float red[8];
  __shared__ float sl[128];
  __shared__ float hb[128];
  __shared__ float scr[2304];
  int bs = blockIdx.x, b = bs >> 3, ss = bs & 7, tid = threadIdx.x;
  if (tid < 5){
    float v = 0.f;
    #pragma unroll
    for (int t7 = 0; t7 < 7; t7++) v += p.hpart_g[((long)(b*7+t7)*8 + ss)*136 + 128 + tid];
    red[tid] = v;
  }
  __syncthreads();
  float SA = red[0], inv = 1.f/SA;
  float Sp0 = red[1]*inv, Sp1 = red[2]*inv;
  float Ss0 = sqrtf(fmaxf(red[3]*inv - Sp0*Sp0, 0.f));
  float Ss1 = sqrtf(fmaxf(red[4]*inv - Sp1*Sp1, 0.f));

  if (LAST){
    if ((b % 5) == 2){
      int clip = b/5;
      long base = (long)NB*NS*DD + ((long)clip*8 + ss)*NT;
      const float* arow = p.a_g + ((long)clip*8 + ss)*NT;
      for (int j = tid; j < NT; j += 256) p.out[base+j] = arow[j]*inv;
    }
    if (tid < 128) sl[tid] = p.slots_g[(long)bs*128+tid];
    __syncthreads();
    int o = tid & 127, h = tid >> 7;
    float acc = 0.f;
    #pragma unroll 4
    for (int k = 0; k < 64; k++) acc = fmaf(sl[h*64+k], p.fin_w[(h*64+k)*128+o], acc);
    scr[h*128+o] = acc;
    __syncthreads();
    if (tid < 128) p.out[(long)bs*128+tid] = p.fin_b[tid] + scr[tid] + scr[128+tid];
    return;
  }

  if (tid < 128){
    float v = 0.f;
    #pragma unroll
    for (int t7 = 0; t7 < 7; t7++) v += p.hpart_g[((long)(b*7+t7)*8 + ss)*136 + tid];
    hb[tid] = v * inv;
    sl[tid] = p.slots_g[(long)bs*128+tid];
  }
  __syncthreads();
  float* part = scr;
  float* upd  = scr + 256;
  float* gil  = scr + 384;
  float* ghl  = scr + 768;
  float* hnl  = scr + 1152;
  float* yv   = scr + 1280;
  float* h1   = scr + 1408;
  int o = tid & 127, h = tid >> 7;
  float acc2 = 0.f;
  #pragma unroll 4
  for (int k = 0; k < 64; k++) acc2 = fmaf(hb[h*64+k], p.Wf2[(h*64+k)*128+o], acc2);
  part[h*128+o] = acc2;
  __syncthreads();
  if (tid < 128) upd[tid] = part[tid] + part[128+tid] + p.bf2[tid];
  __syncthreads();
  int oA = tid, oB = tid + 256;
  float giA = p.gru_b_ih[oA], ghA = p.gru_b_hh[oA];
  float giB = 0.f, ghB = 0.f;
  if (tid < 128){ giB = p.gru_b_ih[oB]; ghB = p.gru_b_hh[oB]; }
  #pragma unroll 4
  for (int k = 0; k < 128; k++){
    float uk = upd[k], sk = sl[k];
    giA = fmaf(uk, p.gru_w_ih[k*384+oA], giA);
    ghA = fmaf(sk, p.gru_w_hh[k*384+oA], ghA);
    if (tid < 128){
      giB = fmaf(uk, p.gru_w_ih[k*384+oB], giB);
      ghB = fmaf(sk, p.gru_w_hh[k*384+oB], ghB);
    }
  }
  gil[oA] = giA; ghl[oA] = ghA;
  if (tid < 128){ gil[oB] = giB; ghl[oB] = ghB; }
  __syncthreads();
  float hnv = 0.f;
  if (tid < 128){
    float r = 1.f/(1.f+expf(-(gil[tid]+ghl[tid])));
    float z = 1.f/(1.f+expf(-(gil[128+tid]+ghl[128+tid])));
    float n = tanhf(gil[256+tid] + r*ghl[256+tid]);
    hnv = (1.f-z)*n + z*sl[tid];
  }
  float t1 = hnv, t2 = hnv*hnv;
  #pragma unroll
  for (int m = 1; m < 64; m <<= 1){ t1 += __shfl_xor(t1,m); t2 += __shfl_xor(t2,m); }
  if (tid < 128 && (tid & 63) == 0){ red[(tid>>6)*2] = t1; red[(tid>>6)*2+1] = t2; }
  __syncthreads();
  float mean = (red[0]+red[2])*(1.f/128.f);
  float var  = (red[1]+red[3])*(1.f/128.f) - mean*mean;
  float rstd = rsqrtf(var + 1e-5f);
  if (tid < 128){
    hnl[tid] = hnv;
    yv[tid] = (hnv-mean)*rstd*p.mlp_ln_g[tid] + p.mlp_ln_b[tid];
  }
  __syncthreads();
  float m1A = p.mlp_b1[tid], m1B = p.mlp_b1[tid+256];
  #pragma unroll 4
  for (int k = 0; k < 128; k++){
    float y = yv[k];
    m1A = fmaf(y, p.mlp_w1[k*512+tid], m1A);
    m1B = fmaf(y, p.mlp_w1[k*512+tid+256], m1B);
  }
  h1[tid] = fmaxf(m1A, 0.f); h1[tid+256] = fmaxf(m1B, 0.f);
  __syncthreads();
  float a2 = 0.f;
  #pragma unroll 4
  for (int kk = 0; kk < 256; kk++) a2 = fmaf(h1[h*256+kk], p.mlp_w2[(h*256+kk)*128+o], a2);
  part[h*128+o] = a2;
  __syncthreads();
  if (tid < 128){
    float sln = hnl[tid] + p.mlp_b2[tid] + part[tid] + part[128+tid];
    sl[tid] = sln;
    p.slots_g[(long)bs*128+tid] = sln;
  }
  __syncthreads();
  phase0g(p, bs, tid, scr, sl, Sp0, Sp1, Ss0, Ss1);
}

extern "C" void kernel_launch(void* const* d_in, const int* in_sizes, int n_in,
                              void* d_out, int out_size, void* d_ws, size_t ws_size,
                              hipStream_t stream){
  PP p;
  p.inputs=(const float*)d_in[0]; p.tok_idx=(const int*)d_in[1]; p.abs_grid=(const float*)d_in[2];
  p.slots_init=(const float*)d_in[3]; p.Sp_init=(const float*)d_in[4]; p.Ss_init=(const float*)d_in[5];
  p.WQ=(const float*)d_in[6]; p.ln_g=(const float*)d_in[7]; p.ln_b=(const float*)d_in[8];
  p.gru_w_ih=(const float*)d_in[9]; p.gru_w_hh=(const float*)d_in[10];
  p.gru_b_ih=(const float*)d_in[11]; p.gru_b_hh=(const float*)d_in[12];
  p.mlp_ln_g=(const float*)d_in[13]; p.mlp_ln_b=(const float*)d_in[14];
  p.mlp_w1=(const float*)d_in[15]; p.mlp_b1=(const float*)d_in[16];
  p.mlp_w2=(const float*)d_in[17]; p.mlp_b2=(const float*)d_in[18];
  p.WK=(const float*)d_in[19]; p.WV=(const float*)d_in[20]; p.Wg=(const float*)d_in[21]; p.bg=(const float*)d_in[22];
  p.Wf1=(const float*)d_in[23]; p.bf1=(const float*)d_in[24]; p.Wf2=(const float*)d_in[25]; p.bf2=(const float*)d_in[26];
  p.im_ln1_g=(const float*)d_in[27]; p.im_ln1_b=(const float*)d_in[28];
  p.im_w1=(const float*)d_in[29]; p.im_b1=(const float*)d_in[30];
  p.im_w2=(const float*)d_in[31]; p.im_b2=(const float*)d_in[32];
  p.im_ln2_g=(const float*)d_in[33]; p.im_ln2_b=(const float*)d_in[34];
  p.fin_w=(const float*)d_in[35]; p.fin_b=(const float*)d_in[36];

  float* w = (float*)d_ws;
  size_t need = 0;
  auto alloc = [&](size_t nfl){ nfl = (nfl + 3) & ~(size_t)3; float* r = w + need; need += nfl; return r; };
  p.A_K  = alloc((size_t)NTOT*DD);
  p.A_V  = alloc((size_t)NTOT*DD);
  p.Wg1  = alloc(2*DD);
  p.c1   = alloc(DD);
  p.Wf2T = alloc(DD*DD);
  p.slots_g = alloc(320*128);
  p.qw_g    = alloc(320*128);
  p.qb_g    = alloc(320);
  p.spss_g  = alloc(320*4);
  p.hpart_g = alloc((size_t)NB*7*8*136);
  p.a_g     = alloc((size_t)8*8*NT);
  p.xnh  = (ushort*)alloc((size_t)NTOT*DIN/2);
  p.xnl  = (ushort*)alloc((size_t)NTOT*DIN/2);
  p.hh   = (ushort*)alloc((size_t)NTOT*DIN/2);
  p.hl   = (ushort*)alloc((size_t)NTOT*DIN/2);
  p.W1Th = (ushort*)alloc((size_t)DIN*DIN/2);
  p.W1Tl = (ushort*)alloc((size_t)DIN*DIN/2);
  p.W2Th = (ushort*)alloc((size_t)DD*DIN/2);
  p.W2Tl = (ushort*)alloc((size_t)DD*DIN/2);
  p.WKfTh = (ushort*)alloc(DD*DD/2);
  p.WKfTl = (ushort*)alloc(DD*DD/2);
  p.WVfTh = (ushort*)alloc(DD*DD/2);
  p.WVfTl = (ushort*)alloc(DD*DD/2);
  p.out = (float*)d_out;
  if (ws_size < need*sizeof(float)){
    fprintf(stderr, "kernel_launch: ws too small (%zu < %zu)\n", ws_size, need*sizeof(float));
    return;
  }

  prep_weights<<<dim3(DD), dim3(128), 0, stream>>>(p);
  transpose_both<<<dim3(168), dim3(256), 0, stream>>>(p);
  ln1_init<<<dim3(4730), dim3(256), 0, stream>>>(p);
  gemm1_128<<<dim3(832), dim3(256), 0, stream>>>(p);
  gemm2_fused<<<dim3((NTOT+31)/32), dim3(256), 0, stream>>>(p);

  for (int t = 0; t < 3; t++){
    kA<0><<<dim3(NB*7), dim3(256), 0, stream>>>(p);
    kB<0><<<dim3(320), dim3(256), 0, stream>>>(p);
  }
  kA<1><<<dim3(NB*7), dim3(256), 0, stream>>>(p);
  kB<1><<<dim3(320), dim3(256), 0, stream>>>(p);
}

// Round 18
// 411.739 us; speedup vs baseline: 1.1245x; 1.1245x over previous
//
#include <hip/hip_runtime.h>
#include <cstdio>

#define NB 40
#define NS 8
#define NT 441
#define DIN 768
#define DD 128
#define NTOT (NB*NT)
#define FSCALE 0.08838834764831843f

typedef short s8v __attribute__((ext_vector_type(8)));
typedef float f4v __attribute__((ext_vector_type(4)));

__device__ inline ushort f2bf(float f){
  unsigned u = __float_as_uint(f);
  unsigned r = (u + 0x7fffu + ((u >> 16) & 1u)) >> 16;
  return (ushort)r;
}
__device__ inline float bf2f(ushort h){ return __uint_as_float(((unsigned)h) << 16); }
__device__ inline float dot4a(float4 a, float4 b, float acc){
  return fmaf(a.w, b.w, fmaf(a.z, b.z, fmaf(a.y, b.y, fmaf(a.x, b.x, acc))));
}

struct PP {
  const float *inputs; const int *tok_idx; const float *abs_grid;
  const float *slots_init, *Sp_init, *Ss_init;
  const float *WQ, *ln_g, *ln_b;
  const float *gru_w_ih, *gru_w_hh, *gru_b_ih, *gru_b_hh;
  const float *mlp_ln_g, *mlp_ln_b, *mlp_w1, *mlp_b1, *mlp_w2, *mlp_b2;
  const float *WK, *WV, *Wg, *bg, *Wf1, *bf1, *Wf2, *bf2;
  const float *im_ln1_g, *im_ln1_b, *im_w1, *im_b1, *im_w2, *im_b2, *im_ln2_g, *im_ln2_b;
  const float *fin_w, *fin_b;
  float *A_K, *A_V, *Wg1, *c1, *Wf2T;
  float *slots_g, *qw_g, *qb_g, *spss_g, *hpart_g, *a_g;
  float4 *WQp, *f2P, *f2TP, *finP, *gihP, *ghhP, *w1P, *w2P;
  ushort *xnh, *xnl, *hh, *hl, *W1Th, *W1Tl, *W2Th, *W2Tl;
  ushort *WKfTh, *WKfTl, *WVfTh, *WVfTl;
  float *out;
};

// ---------- weight prep ----------
__global__ __launch_bounds__(128) void prep_weights(PP p){
  int r = blockIdx.x, d = threadIdx.x;
  float accK = 0.f, accV = 0.f;
  for (int kk = 0; kk < DD; kk++){
    float w = p.Wf1[kk*DD + d];
    accK = fmaf(p.WK[r*DD+kk], w, accK);
    accV = fmaf(p.WV[r*DD+kk], w, accV);
  }
  ushort hk = f2bf(accK), hv = f2bf(accV);
  p.WKfTh[d*DD + r] = hk; p.WKfTl[d*DD + r] = f2bf(accK - bf2f(hk));
  p.WVfTh[d*DD + r] = hv; p.WVfTl[d*DD + r] = f2bf(accV - bf2f(hv));
  if (r < 2){
    float a = 0.f;
    for (int kk = 0; kk < DD; kk++) a = fmaf(p.Wg[r*DD+kk], p.Wf1[kk*DD+d], a);
    p.Wg1[r*DD+d] = a;
  }
  if (r == 2){
    float a = 0.f;
    for (int kk = 0; kk < DD; kk++) a = fmaf(p.bg[kk], p.Wf1[kk*DD+d], a);
    p.c1[d] = a + p.bf1[d];
  }
  p.Wf2T[d*DD + r] = p.Wf2[r*DD + d];
}

// ---------- pack weights into coalesced float4-over-k layout ----------
// P[k4*N + o] = {W[4k4][o], W[4k4+1][o], W[4k4+2][o], W[4k4+3][o]}
__global__ __launch_bounds__(256) void prep_pack(PP p){
  long i = (long)blockIdx.x*256 + threadIdx.x;
  const float* src; float4* dst; int N; long base;
  if      (i < 4096) { src = p.WQ;        dst = p.WQp;  N = 128; base = 0; }
  else if (i < 8192) { src = p.Wf2;       dst = p.f2P;  N = 128; base = 4096; }
  else if (i < 12288){ src = p.Wf2T;      dst = p.f2TP; N = 128; base = 8192; }
  else if (i < 16384){ src = p.fin_w;     dst = p.finP; N = 128; base = 12288; }
  else if (i < 28672){ src = p.gru_w_ih;  dst = p.gihP; N = 384; base = 16384; }
  else if (i < 40960){ src = p.gru_w_hh;  dst = p.ghhP; N = 384; base = 28672; }
  else if (i < 57344){ src = p.mlp_w1;    dst = p.w1P;  N = 512; base = 40960; }
  else               { src = p.mlp_w2;    dst = p.w2P;  N = 128; base = 57344; }
  long j = i - base;
  long k4 = j / N, o = j % N;
  float4 v;
  v.x = src[(k4*4+0)*N+o]; v.y = src[(k4*4+1)*N+o];
  v.z = src[(k4*4+2)*N+o]; v.w = src[(k4*4+3)*N+o];
  dst[j] = v;
}

// ---------- combined transpose + bf16 split for im_w1 and im_w2 ----------
__global__ __launch_bounds__(256) void transpose_both(PP p){
  __shared__ float tile[64][65];
  int t = blockIdx.x;
  const float* W; ushort *WTh, *WTl; int N, k0, n0;
  if (t < 144){ W = p.im_w1; WTh = p.W1Th; WTl = p.W1Tl; N = 768; k0 = (t/12)*64; n0 = (t%12)*64; }
  else { t -= 144; W = p.im_w2; WTh = p.W2Th; WTl = p.W2Tl; N = 128; k0 = (t/2)*64; n0 = (t&1)*64; }
  int tid = threadIdx.x;
  #pragma unroll
  for (int i = 0; i < 4; i++){
    int k = i*16 + (tid >> 4);
    int n4 = (tid & 15) * 4;
    float4 v = *(const float4*)(W + (long)(k0+k)*N + n0 + n4);
    tile[k][n4+0] = v.x; tile[k][n4+1] = v.y; tile[k][n4+2] = v.z; tile[k][n4+3] = v.w;
  }
  __syncthreads();
  #pragma unroll
  for (int i = 0; i < 4; i++){
    int n = i*16 + (tid >> 4);
    int k4 = (tid & 15) * 4;
    ushort4 h4, l4;
    float v0 = tile[k4+0][n], v1 = tile[k4+1][n], v2 = tile[k4+2][n], v3 = tile[k4+3][n];
    h4.x = f2bf(v0); l4.x = f2bf(v0 - bf2f(h4.x));
    h4.y = f2bf(v1); l4.y = f2bf(v1 - bf2f(h4.y));
    h4.z = f2bf(v2); l4.z = f2bf(v2 - bf2f(h4.z));
    h4.w = f2bf(v3); l4.w = f2bf(v3 - bf2f(h4.w));
    *(ushort4*)(WTh + (long)(n0+n)*DIN + k0 + k4) = h4;
    *(ushort4*)(WTl + (long)(n0+n)*DIN + k0 + k4) = l4;
  }
}

// ---------- phase0 (float4-packed matvecs) ----------
__device__ void phase0g(const PP& p, int bs, int tid, float* scr, const float* sl,
                        float Sp0, float Sp1, float Ss0, float Ss1){
  float* sn   = scr;
  float* qv   = scr + 128;
  float* part = scr + 256;
  float* red  = scr + 512;
  int o = tid & 127, h = tid >> 7;
  float v = (tid < 128) ? sl[tid] : 0.f;
  float s1 = v, s2 = v*v;
  #pragma unroll
  for (int m = 1; m < 64; m <<= 1){ s1 += __shfl_xor(s1,m); s2 += __shfl_xor(s2,m); }
  if (tid < 128 && (tid & 63) == 0){ red[(tid>>6)*2] = s1; red[(tid>>6)*2+1] = s2; }
  __syncthreads();
  float mean = (red[0]+red[2])*(1.f/128.f);
  float var  = (red[1]+red[3])*(1.f/128.f) - mean*mean;
  float rstd = rsqrtf(var + 1e-5f);
  if (tid < 128) sn[tid] = (v-mean)*rstd*p.ln_g[tid] + p.ln_b[tid];
  __syncthreads();
  float acc = 0.f;
  for (int k4 = 0; k4 < 16; k4++){
    float4 sv = *(const float4*)&sn[h*64 + k4*4];
    float4 wv = p.WQp[(h*16 + k4)*128 + o];
    acc = dot4a(sv, wv, acc);
  }
  part[h*128+o] = acc;
  __syncthreads();
  if (tid < 128) qv[tid] = part[tid] + part[128+tid];
  __syncthreads();
  float acc2 = 0.f;
  for (int k4 = 0; k4 < 16; k4++){
    float4 qv4 = *(const float4*)&qv[h*64 + k4*4];
    float4 wv  = p.f2TP[(h*16 + k4)*128 + o];
    acc2 = dot4a(qv4, wv, acc2);
  }
  part[h*128+o] = acc2;
  __syncthreads();
  if (tid < 128) p.qw_g[(long)bs*128+tid] = part[tid] + part[128+tid];
  float pb = (tid < 128) ? qv[tid]*p.bf2[tid] : 0.f;
  #pragma unroll
  for (int m = 1; m < 64; m <<= 1) pb += __shfl_xor(pb,m);
  if ((tid & 63) == 0) red[4 + (tid>>6)] = pb;
  __syncthreads();
  if (tid == 0){
    p.qb_g[bs] = FSCALE*(red[4]+red[5]+red[6]+red[7]);
    p.spss_g[bs*4+0] = Sp0; p.spss_g[bs*4+1] = Sp1;
    p.spss_g[bs*4+2] = 1.f/(Ss0*5.0f); p.spss_g[bs*4+3] = 1.f/(Ss1*5.0f);
  }
}

// ---------- LN1+split (blocks 0..4409) and slot init (blocks 4410..4729) ----------
__global__ __launch_bounds__(256) void ln1_init(PP p){
  __shared__ __align__(16) float sl[128];
  __shared__ __align__(16) float scr[520];
  if (blockIdx.x < 4410){
    int tok = blockIdx.x*4 + (threadIdx.x >> 6);
    int l = threadIdx.x & 63;
    const float* src = p.inputs + (long)tok*DIN;
    float4 v[3];
    float s = 0.f, s2 = 0.f;
    #pragma unroll
    for (int pp = 0; pp < 3; pp++){
      v[pp] = *(const float4*)(src + pp*256 + l*4);
      s  += v[pp].x + v[pp].y + v[pp].z + v[pp].w;
      s2 += v[pp].x*v[pp].x + v[pp].y*v[pp].y + v[pp].z*v[pp].z + v[pp].w*v[pp].w;
    }
    #pragma unroll
    for (int m = 1; m < 64; m <<= 1){ s += __shfl_xor(s, m); s2 += __shfl_xor(s2, m); }
    float mean = s*(1.f/DIN), var = s2*(1.f/DIN) - mean*mean;
    float rstd = rsqrtf(var + 1e-5f);
    #pragma unroll
    for (int pp = 0; pp < 3; pp++){
      int idx = pp*256 + l*4;
      float4 g = *(const float4*)(p.im_ln1_g + idx);
      float4 b = *(const float4*)(p.im_ln1_b + idx);
      float y0 = (v[pp].x-mean)*rstd*g.x + b.x;
      float y1 = (v[pp].y-mean)*rstd*g.y + b.y;
      float y2 = (v[pp].z-mean)*rstd*g.z + b.z;
      float y3 = (v[pp].w-mean)*rstd*g.w + b.w;
      ushort4 h4, l4;
      h4.x = f2bf(y0); l4.x = f2bf(y0 - bf2f(h4.x));
      h4.y = f2bf(y1); l4.y = f2bf(y1 - bf2f(h4.y));
      h4.z = f2bf(y2); l4.z = f2bf(y2 - bf2f(h4.z));
      h4.w = f2bf(y3); l4.w = f2bf(y3 - bf2f(h4.w));
      *(ushort4*)(p.xnh + (long)tok*DIN + idx) = h4;
      *(ushort4*)(p.xnl + (long)tok*DIN + idx) = l4;
    }
  } else {
    int bs = blockIdx.x - 4410, ss = bs & 7, tid = threadIdx.x;
    if (tid < 128){
      float v = p.slots_init[ss*128+tid];
      sl[tid] = v;
      p.slots_g[(long)bs*128+tid] = v;
    }
    __syncthreads();
    phase0g(p, bs, tid, scr, sl,
            p.Sp_init[ss*2], p.Sp_init[ss*2+1], p.Ss_init[ss*2], p.Ss_init[ss*2+1]);
  }
}

// ---------- GEMM1: 128x128, XCD m-grouping, swizzled global_load_lds, 2-phase dbuf ----------
__global__ __launch_bounds__(256, 2) void gemm1_128(PP p){
  __shared__ __align__(16) ushort LDSm[32768];
  int id = blockIdx.x;
  int xcd = id & 7, idx = id >> 3;
  int m_t = xcd + 8*(idx/6), n_t = idx % 6;
  if (m_t >= 138) return;
  int m0 = m_t*128, n0 = n_t*128;
  int tid = threadIdx.x;
  int w = tid >> 6, lane = tid & 63;
  int wm = w >> 1, wn = w & 1;
  int lch = lane ^ ((lane >> 3) & 7);
  int r_in = lch >> 2, kgs = lch & 3;
  const ushort* S = (w == 0) ? p.xnh : (w == 1) ? p.xnl : (w == 2) ? p.W1Th : p.W1Tl;
  int base0 = (w < 2) ? m0 : n0;
  bool isA = (w < 2);
  int kg = lane >> 4, rA = lane & 15;
  int cc = rA*4 + kg;
  int cs = cc ^ ((cc >> 3) & 7);
  const char* LB = (const char*)LDSm;

  f4v acc[4][4];
  #pragma unroll
  for (int mf = 0; mf < 4; mf++)
    #pragma unroll
    for (int nf = 0; nf < 4; nf++) acc[mf][nf] = (f4v)(0.f);

  #pragma unroll
  for (int t = 0; t < 8; t++){
    int grow = base0 + t*16 + r_in;
    if (isA) grow = min(grow, NTOT-1);
    const ushort* gptr = S + (long)grow*DIN + 0 + kgs*8;
    ushort* lptr = &LDSm[w*4096 + t*512];
    __builtin_amdgcn_global_load_lds(
        (const __attribute__((address_space(1))) void*)gptr,
        (__attribute__((address_space(3))) void*)lptr, 16, 0, 0);
  }
  __syncthreads();

  int cur = 0;
  for (int kb = 0; kb < DIN; kb += 32){
    if (kb + 32 < DIN){
      int nb = cur ^ 1;
      #pragma unroll
      for (int t = 0; t < 8; t++){
        int grow = base0 + t*16 + r_in;
        if (isA) grow = min(grow, NTOT-1);
        const ushort* gptr = S + (long)grow*DIN + (kb + 32) + kgs*8;
        ushort* lptr = &LDSm[nb*16384 + w*4096 + t*512];
        __builtin_amdgcn_global_load_lds(
            (const __attribute__((address_space(1))) void*)gptr,
            (__attribute__((address_space(3))) void*)lptr, 16, 0, 0);
      }
    }
    const char* B = LB + cur*32768;
    s8v a0[4], a1[4], b0[4], b1[4];
    #pragma unroll
    for (int mf = 0; mf < 4; mf++){
      int win = wm*4 + mf;
      a0[mf] = *(const s8v*)(B +         win*1024 + cs*16);
      a1[mf] = *(const s8v*)(B +  8192 + win*1024 + cs*16);
    }
    #pragma unroll
    for (int nf = 0; nf < 4; nf++){
      int win = wn*4 + nf;
      b0[nf] = *(const s8v*)(B + 16384 + win*1024 + cs*16);
      b1[nf] = *(const s8v*)(B + 24576 + win*1024 + cs*16);
    }
    #pragma unroll
    for (int mf = 0; mf < 4; mf++)
      #pragma unroll
      for (int nf = 0; nf < 4; nf++){
        acc[mf][nf] = __builtin_amdgcn_mfma_f32_16x16x32_bf16(a0[mf], b0[nf], acc[mf][nf], 0, 0, 0);
        acc[mf][nf] = __builtin_amdgcn_mfma_f32_16x16x32_bf16(a0[mf], b1[nf], acc[mf][nf], 0, 0, 0);
        acc[mf][nf] = __builtin_amdgcn_mfma_f32_16x16x32_bf16(a1[mf], b0[nf], acc[mf][nf], 0, 0, 0);
      }
    __syncthreads();
    cur ^= 1;
  }

  int rbase = (lane >> 4) * 4, cn = lane & 15;
  #pragma unroll
  for (int mf = 0; mf < 4; mf++)
    #pragma unroll
    for (int nf = 0; nf < 4; nf++){
      int n = n0 + wn*64 + nf*16 + cn;
      float bs = p.im_b1[n];
      #pragma unroll
      for (int r = 0; r < 4; r++){
        int m = m0 + wm*64 + mf*16 + rbase + r;
        if (m < NTOT){
          float v = fmaxf(acc[mf][nf][r] + bs, 0.f);
          ushort h = f2bf(v);
          p.hh[(long)m*DIN + n] = h;
          p.hl[(long)m*DIN + n] = f2bf(v - bf2f(h));
        }
      }
    }
}

// ---------- GEMM2 fused, BM=32 ----------
__global__ __launch_bounds__(256) void gemm2_fused(PP p){
  __shared__ __align__(16) char smem[43008];
  ushort* As = (ushort*)smem;
  ushort* Bs = (ushort*)(smem + 5120);
  float*  Dl = (float*)smem;
  ushort* xsh = (ushort*)(smem + 25600);
  ushort* xsl = (ushort*)(smem + 25600 + 8704);
  int m0 = blockIdx.x * 32;
  int tid = threadIdx.x, w = tid >> 6, lane = tid & 63;
  f4v acc[2][2];
  #pragma unroll
  for (int mf = 0; mf < 2; mf++)
    #pragma unroll
    for (int nf = 0; nf < 2; nf++) acc[mf][nf] = (f4v)(0.f);

  for (int kb = 0; kb < DIN; kb += 32){
    __syncthreads();
    {
      int c = tid;
      int s = c >> 7, rem = c & 127, r = rem >> 2, kg = rem & 3;
      int gr = min(m0 + r, NTOT-1);
      const float4 va = *(const float4*)((s ? p.hl : p.hh) + (long)gr*DIN + kb + kg*8);
      *(float4*)(As + s*1280 + r*40 + kg*8) = va;
    }
    #pragma unroll
    for (int i = 0; i < 4; i++){
      int c = tid + i*256;
      int s = c >> 9, r = (c >> 2) & 127, kg = c & 3;
      const float4 vb = *(const float4*)((s ? p.W2Tl : p.W2Th) + (long)r*DIN + kb + kg*8);
      *(float4*)(Bs + s*5120 + r*40 + kg*8) = vb;
    }
    __syncthreads();
    int kg = lane >> 4, rA = lane & 15;
    s8v a0[2], a1[2], b0[2], b1[2];
    #pragma unroll
    for (int mf = 0; mf < 2; mf++){
      a0[mf] = *(const s8v*)(As +        (mf*16 + rA)*40 + kg*8);
      a1[mf] = *(const s8v*)(As + 1280 + (mf*16 + rA)*40 + kg*8);
    }
    #pragma unroll
    for (int nf = 0; nf < 2; nf++){
      int rb = w*32 + nf*16 + rA;
      b0[nf] = *(const s8v*)(Bs +        rb*40 + kg*8);
      b1[nf] = *(const s8v*)(Bs + 5120 + rb*40 + kg*8);
    }
    #pragma unroll
    for (int mf = 0; mf < 2; mf++)
      #pragma unroll
      for (int nf = 0; nf < 2; nf++){
        acc[mf][nf] = __builtin_amdgcn_mfma_f32_16x16x32_bf16(a0[mf], b0[nf], acc[mf][nf], 0, 0, 0);
        acc[mf][nf] = __builtin_amdgcn_mfma_f32_16x16x32_bf16(a0[mf], b1[nf], acc[mf][nf], 0, 0, 0);
        acc[mf][nf] = __builtin_amdgcn_mfma_f32_16x16x32_bf16(a1[mf], b0[nf], acc[mf][nf], 0, 0, 0);
      }
  }

  int rbase = (lane >> 4) * 4, cn = lane & 15;
  __syncthreads();
  #pragma unroll
  for (int mf = 0; mf < 2; mf++)
    #pragma unroll
    for (int nf = 0; nf < 2; nf++){
      int n = w*32 + nf*16 + cn;
      float bs = p.im_b2[n];
      #pragma unroll
      for (int r = 0; r < 4; r++)
        Dl[(mf*16 + rbase + r)*132 + n] = acc[mf][nf][r] + bs;
    }
  __syncthreads();
  for (int rr = 0; rr < 8; rr++){
    int row = w*8 + rr;
    float e0 = Dl[row*132 + lane], e1 = Dl[row*132 + 64 + lane];
    float s = e0 + e1, s2 = e0*e0 + e1*e1;
    #pragma unroll
    for (int m2 = 1; m2 < 64; m2 <<= 1){ s += __shfl_xor(s, m2); s2 += __shfl_xor(s2, m2); }
    float mean = s*(1.f/DD), var = s2*(1.f/DD) - mean*mean;
    float rstd = rsqrtf(var + 1e-5f);
    float x0 = (e0-mean)*rstd*p.im_ln2_g[lane]    + p.im_ln2_b[lane];
    float x1 = (e1-mean)*rstd*p.im_ln2_g[64+lane] + p.im_ln2_b[64+lane];
    ushort h0 = f2bf(x0), h1 = f2bf(x1);
    xsh[row*136 + lane]      = h0;  xsl[row*136 + lane]      = f2bf(x0 - bf2f(h0));
    xsh[row*136 + 64 + lane] = h1;  xsl[row*136 + 64 + lane] = f2bf(x1 - bf2f(h1));
  }
  __syncthreads();
  int kg = lane >> 4, rA = lane & 15;
  int kv = w >> 1, rowblk = w & 1;
  const ushort* WTh = kv ? p.WVfTh : p.WKfTh;
  const ushort* WTl = kv ? p.WVfTl : p.WKfTl;
  float* OUT = kv ? p.A_V : p.A_K;
  f4v aO[8];
  #pragma unroll
  for (int nf = 0; nf < 8; nf++) aO[nf] = (f4v)(0.f);
  #pragma unroll
  for (int kb2 = 0; kb2 < 4; kb2++){
    s8v ah = *(const s8v*)&xsh[(rowblk*16+rA)*136 + kb2*32 + kg*8];
    s8v al = *(const s8v*)&xsl[(rowblk*16+rA)*136 + kb2*32 + kg*8];
    #pragma unroll
    for (int nf = 0; nf < 8; nf++){
      int n = nf*16 + rA;
      s8v bh = *(const s8v*)(WTh + n*DD + kb2*32 + kg*8);
      s8v bl = *(const s8v*)(WTl + n*DD + kb2*32 + kg*8);
      aO[nf] = __builtin_amdgcn_mfma_f32_16x16x32_bf16(ah, bh, aO[nf], 0, 0, 0);
      aO[nf] = __builtin_amdgcn_mfma_f32_16x16x32_bf16(ah, bl, aO[nf], 0, 0, 0);
      aO[nf] = __builtin_amdgcn_mfma_f32_16x16x32_bf16(al, bh, aO[nf], 0, 0, 0);
    }
  }
  #pragma unroll
  for (int nf = 0; nf < 8; nf++){
    int n = nf*16 + cn;
    float c = p.c1[n];
    #pragma unroll
    for (int r = 0; r < 4; r++){
      int m = m0 + rowblk*16 + rbase + r;
      if (m < NTOT) OUT[(long)m*DD + n] = aO[nf][r] + c;
    }
  }
}

// ---------- kA ----------
template<int LAST>
__global__ __launch_bounds__(256) void kA(PP p){
  int b = blockIdx.x / 7, tile = blockIdx.x % 7;
  int tid = threadIdx.x, wid = tid >> 6, lane = tid & 63;
  __shared__ float qws[8][132];
  __shared__ float qbs[8];
  __shared__ float spssL[32];
  __shared__ float agt[64][2];
  __shared__ float a_tile[8][64];
  __shared__ float hpartL[4][8][128];
  for (int f = tid; f < 8*128; f += 256){
    int s = f >> 7, d = f & 127;
    qws[s][(d&31)*4 + (d>>5)] = p.qw_g[((long)b*8+s)*128 + d];
  }
  if (tid < 8)  qbs[tid] = p.qb_g[b*8+tid];
  if (tid < 32) spssL[tid] = p.spss_g[b*32+tid];
  if (tid < 64){
    int j = tile*64 + tid;
    float g0 = 0.f, g1 = 0.f;
    if (j < NT){ int idx = p.tok_idx[b*NT+j]; g0 = p.abs_grid[idx*2]; g1 = p.abs_grid[idx*2+1]; }
    agt[tid][0] = g0; agt[tid][1] = g1;
  }
  __syncthreads();

  {
    int tl = lane >> 2, dg = lane & 3;
    int jtok = wid*16 + tl, j = tile*64 + jtok;
    bool valid = j < NT;
    int jc = valid ? j : 0;
    float aa[32], w0[32], w1[32];
    const float* src = p.A_K + ((long)(b*NT+jc))*DD + dg*32;
    #pragma unroll
    for (int i4 = 0; i4 < 8; i4++){
      float4 t = *(const float4*)(src + i4*4);
      aa[i4*4+0]=t.x; aa[i4*4+1]=t.y; aa[i4*4+2]=t.z; aa[i4*4+3]=t.w;
    }
    #pragma unroll
    for (int i4 = 0; i4 < 8; i4++){
      float4 t0 = *(const float4*)(p.Wg1 + dg*32 + i4*4);
      float4 t1 = *(const float4*)(p.Wg1 + DD + dg*32 + i4*4);
      w0[i4*4+0]=t0.x; w0[i4*4+1]=t0.y; w0[i4*4+2]=t0.z; w0[i4*4+3]=t0.w;
      w1[i4*4+0]=t1.x; w1[i4*4+1]=t1.y; w1[i4*4+2]=t1.z; w1[i4*4+3]=t1.w;
    }
    float ag0 = agt[jtok][0], ag1 = agt[jtok][1];
    float dv[8];
    #pragma unroll
    for (int s = 0; s < 8; s++){
      float rel0 = (ag0 - spssL[s*4+0])*spssL[s*4+2];
      float rel1 = (ag1 - spssL[s*4+1])*spssL[s*4+3];
      float acc = 0.f;
      #pragma unroll
      for (int i = 0; i < 32; i++){
        float hk = fmaxf(fmaf(rel0, w0[i], fmaf(rel1, w1[i], aa[i])), 0.f);
        acc = fmaf(hk, qws[s][i*4+dg], acc);
      }
      acc += __shfl_xor(acc, 1); acc += __shfl_xor(acc, 2);
      dv[s] = acc*FSCALE + qbs[s];
    }
    if (dg == 0){
      float m = -1e30f;
      #pragma unroll
      for (int s = 0; s < 8; s++) m = fmaxf(m, dv[s]);
      float tot = 0.f;
      #pragma unroll
      for (int s = 0; s < 8; s++){ dv[s] = expf(dv[s]-m); tot += dv[s]; }
      float inv = 1.f/tot;
      #pragma unroll
      for (int s = 0; s < 8; s++)
        a_tile[s][jtok] = valid ? (dv[s]*inv + 1e-8f) : 0.f;
    }
  }
  __syncthreads();

  #pragma unroll
  for (int si = 0; si < 2; si++){
    int s = wid*2 + si;
    float a = a_tile[s][lane];
    float g0 = agt[lane][0], g1 = agt[lane][1];
    float v0 = a, v1 = a*g0, v2 = a*g1, v3 = a*g0*g0, v4 = a*g1*g1;
    #pragma unroll
    for (int m = 1; m < 64; m <<= 1){
      v0 += __shfl_xor(v0,m); v1 += __shfl_xor(v1,m); v2 += __shfl_xor(v2,m);
      v3 += __shfl_xor(v3,m); v4 += __shfl_xor(v4,m);
    }
    if (lane == 0){
      float* st = p.hpart_g + ((long)(b*7+tile)*8 + s)*136 + 128;
      st[0]=v0; st[1]=v1; st[2]=v2; st[3]=v3; st[4]=v4;
    }
  }

  if (LAST){
    if ((b % 5) == 2){
      int clip = b/5;
      for (int f = tid; f < 8*64; f += 256){
        int s = f >> 6, jt = f & 63;
        int j = tile*64 + jt;
        if (j < NT) p.a_g[((long)clip*8 + s)*NT + j] = a_tile[s][jt];
      }
    }
    return;
  }

  {
    float sp0[8], sp1[8], si0[8], si1[8];
    #pragma unroll
    for (int s = 0; s < 8; s++){
      sp0[s]=spssL[s*4+0]; sp1[s]=spssL[s*4+1]; si0[s]=spssL[s*4+2]; si1[s]=spssL[s*4+3];
    }
    int d0 = lane, d1 = lane + 64;
    float wg0a = p.Wg1[d0], wg1a = p.Wg1[DD+d0];
    float wg0b = p.Wg1[d1], wg1b = p.Wg1[DD+d1];
    float acc0[8], acc1[8];
    #pragma unroll
    for (int s = 0; s < 8; s++){ acc0[s]=0.f; acc1[s]=0.f; }
    for (int jj = wid; jj < 64; jj += 4){
      int j = tile*64 + jj;
      if (j >= NT) continue;
      float av0 = p.A_V[((long)(b*NT+j))*DD + d0];
      float av1 = p.A_V[((long)(b*NT+j))*DD + d1];
      float g0 = agt[jj][0], g1 = agt[jj][1];
      #pragma unroll
      for (int s = 0; s < 8; s++){
        float rel0 = (g0 - sp0[s])*si0[s];
        float rel1 = (g1 - sp1[s])*si1[s];
        float a = a_tile[s][jj];
        float hv0 = fmaxf(fmaf(rel0, wg0a, fmaf(rel1, wg1a, av0)), 0.f);
        float hv1 = fmaxf(fmaf(rel0, wg0b, fmaf(rel1, wg1b, av1)), 0.f);
        acc0[s] = fmaf(a, hv0, acc0[s]);
        acc1[s] = fmaf(a, hv1, acc1[s]);
      }
    }
    #pragma unroll
    for (int s = 0; s < 8; s++){ hpartL[wid][s][d0] = acc0[s]; hpartL[wid][s][d1] = acc1[s]; }
    __syncthreads();
    for (int f = tid; f < 1024; f += 256){
      int s = f >> 7, d = f & 127;
      p.hpart_g[((long)(b*7+tile)*8 + s)*136 + d] =
        hpartL[0][s][d] + hpartL[1][s][d] + hpartL[2][s][d] + hpartL[3][s][d];
    }
  }
}

// ---------- kB (float4-packed matvecs) ----------
template<int LAST>
__global__ __launch_bounds__(256) void kB(PP p){
  __shared__ __align__(16) float red[8];
  __shared__ __align__(16) float sl[128];
  __shared__ __align__(16) float hb[128];
  __shared__ __align__(16) float scr[2304];
  int bs = blockIdx.x, b = bs >> 3, ss = bs & 7, tid = threadIdx.x;
  if (tid < 5){
    float v = 0.f;
    #pragma unroll
    for (int t7 = 0; t7 < 7; t7++) v += p.hpart_g[((long)(b*7+t7)*8 + ss)*136 + 128 + tid];
    red[tid] = v;
  }
  __syncthreads();
  float SA = red[0], inv = 1.f/SA;
  float Sp0 = red[1]*inv, Sp1 = red[2]*inv;
  float Ss0 = sqrtf(fmaxf(red[3]*inv - Sp0*Sp0, 0.f));
  float Ss1 = sqrtf(fmaxf(red[4]*inv - Sp1*Sp1, 0.f));

  if (LAST){
    if ((b % 5) == 2){
      int clip = b/5;
      long base = (long)NB*NS*DD + ((long)clip*8 + ss)*NT;
      const float* arow = p.a_g + ((long)clip*8 + ss)*NT;
      for (int j = tid; j < NT; j += 256) p.out[base+j] = arow[j]*inv;
    }
    if (tid < 128) sl[tid] = p.slots_g[(long)bs*128+tid];
    __syncthreads();
    int o = tid & 127, h = tid >> 7;
    float acc = 0.f;
    for (int k4 = 0; k4 < 16; k4++){
      float4 sv = *(const float4*)&sl[h*64 + k4*4];
      float4 wv = p.finP[(h*16 + k4)*128 + o];
      acc = dot4a(sv, wv, acc);
    }
    scr[h*128+o] = acc;
    __syncthreads();
    if (tid < 128) p.out[(long)bs*128+tid] = p.fin_b[tid] + scr[tid] + scr[128+tid];
    return;
  }

  if (tid < 128){
    float v = 0.f;
    #pragma unroll
    for (int t7 = 0; t7 < 7; t7++) v += p.hpart_g[((long)(b*7+t7)*8 + ss)*136 + tid];
    hb[tid] = v * inv;
    sl[tid] = p.slots_g[(long)bs*128+tid];
  }
  __syncthreads();
  float* part = scr;
  float* upd  = scr + 256;
  float* gil  = scr + 384;
  float* ghl  = scr + 768;
  float* hnl  = scr + 1152;
  float* yv   = scr + 1280;
  float* h1   = scr + 1408;
  int o = tid & 127, h = tid >> 7;
  float acc2 = 0.f;
  for (int k4 = 0; k4 < 16; k4++){
    float4 hv = *(const float4*)&hb[h*64 + k4*4];
    float4 wv = p.f2P[(h*16 + k4)*128 + o];
    acc2 = dot4a(hv, wv, acc2);
  }
  part[h*128+o] = acc2;
  __syncthreads();
  if (tid < 128) upd[tid] = part[tid] + part[128+tid] + p.bf2[tid];
  __syncthreads();
  int oA = tid, oB = tid + 256;
  float giA = p.gru_b_ih[oA], ghA = p.gru_b_hh[oA];
  float giB = 0.f, ghB = 0.f;
  if (tid < 128){ giB = p.gru_b_ih[oB]; ghB = p.gru_b_hh[oB]; }
  for (int k4 = 0; k4 < 32; k4++){
    float4 u4 = *(const float4*)&upd[k4*4];
    float4 s4 = *(const float4*)&sl[k4*4];
    float4 wiA = p.gihP[k4*384 + oA];
    float4 whA = p.ghhP[k4*384 + oA];
    giA = dot4a(u4, wiA, giA);
    ghA = dot4a(s4, whA, ghA);
    if (tid < 128){
      float4 wiB = p.gihP[k4*384 + oB];
      float4 whB = p.ghhP[k4*384 + oB];
      giB = dot4a(u4, wiB, giB);
      ghB = dot4a(s4, whB, ghB);
    }
  }
  gil[oA] = giA; ghl[oA] = ghA;
  if (tid < 128){ gil[oB] = giB; ghl[oB] = ghB; }
  __syncthreads();
  float hnv = 0.f;
  if (tid < 128){
    float r = 1.f/(1.f+expf(-(gil[tid]+ghl[tid])));
    float z = 1.f/(1.f+expf(-(gil[128+tid]+ghl[128+tid])));
    float n = tanhf(gil[256+tid] + r*ghl[256+tid]);
    hnv = (1.f-z)*n + z*sl[tid];
  }
  float t1 = hnv, t2 = hnv*hnv;
  #pragma unroll
  for (int m = 1; m < 64; m <<= 1){ t1 += __shfl_xor(t1,m); t2 += __shfl_xor(t2,m); }
  if (tid < 128 && (tid & 63) == 0){ red[(tid>>6)*2] = t1; red[(tid>>6)*2+1] = t2; }
  __syncthreads();
  float mean = (red[0]+red[2])*(1.f/128.f);
  float var  = (red[1]+red[3])*(1.f/128.f) - mean*mean;
  float rstd = rsqrtf(var + 1e-5f);
  if (tid < 128){
    hnl[tid] = hnv;
    yv[tid] = (hnv-mean)*rstd*p.mlp_ln_g[tid] + p.mlp_ln_b[tid];
  }
  __syncthreads();
  float m1A = p.mlp_b1[tid], m1B = p.mlp_b1[tid+256];
  for (int k4 = 0; k4 < 32; k4++){
    float4 y4 = *(const float4*)&yv[k4*4];
    float4 wA = p.w1P[k4*512 + tid];
    float4 wB = p.w1P[k4*512 + tid + 256];
    m1A = dot4a(y4, wA, m1A);
    m1B = dot4a(y4, wB, m1B);
  }
  h1[tid] = fmaxf(m1A, 0.f); h1[tid+256] = fmaxf(m1B, 0.f);
  __syncthreads();
  float a2 = 0.f;
  for (int k4 = 0; k4 < 64; k4++){
    float4 h4 = *(const float4*)&h1[h*256 + k4*4];
    float4 wv = p.w2P[(h*64 + k4)*128 + o];
    a2 = dot4a(h4, wv, a2);
  }
  part[h*128+o] = a2;
  __syncthreads();
  if (tid < 128){
    float sln = hnl[tid] + p.mlp_b2[tid] + part[tid] + part[128+tid];
    sl[tid] = sln;
    p.slots_g[(long)bs*128+tid] = sln;
  }
  __syncthreads();
  phase0g(p, bs, tid, scr, sl, Sp0, Sp1, Ss0, Ss1);
}

extern "C" void kernel_launch(void* const* d_in, const int* in_sizes, int n_in,
                              void* d_out, int out_size, void* d_ws, size_t ws_size,
                              hipStream_t stream){
  PP p;
  p.inputs=(const float*)d_in[0]; p.tok_idx=(const int*)d_in[1]; p.abs_grid=(const float*)d_in[2];
  p.slots_init=(const float*)d_in[3]; p.Sp_init=(const float*)d_in[4]; p.Ss_init=(const float*)d_in[5];
  p.WQ=(const float*)d_in[6]; p.ln_g=(const float*)d_in[7]; p.ln_b=(const float*)d_in[8];
  p.gru_w_ih=(const float*)d_in[9]; p.gru_w_hh=(const float*)d_in[10];
  p.gru_b_ih=(const float*)d_in[11]; p.gru_b_hh=(const float*)d_in[12];
  p.mlp_ln_g=(const float*)d_in[13]; p.mlp_ln_b=(const float*)d_in[14];
  p.mlp_w1=(const float*)d_in[15]; p.mlp_b1=(const float*)d_in[16];
  p.mlp_w2=(const float*)d_in[17]; p.mlp_b2=(const float*)d_in[18];
  p.WK=(const float*)d_in[19]; p.WV=(const float*)d_in[20]; p.Wg=(const float*)d_in[21]; p.bg=(const float*)d_in[22];
  p.Wf1=(const float*)d_in[23]; p.bf1=(const float*)d_in[24]; p.Wf2=(const float*)d_in[25]; p.bf2=(const float*)d_in[26];
  p.im_ln1_g=(const float*)d_in[27]; p.im_ln1_b=(const float*)d_in[28];
  p.im_w1=(const float*)d_in[29]; p.im_b1=(const float*)d_in[30];
  p.im_w2=(const float*)d_in[31]; p.im_b2=(const float*)d_in[32];
  p.im_ln2_g=(const float*)d_in[33]; p.im_ln2_b=(const float*)d_in[34];
  p.fin_w=(const float*)d_in[35]; p.fin_b=(const float*)d_in[36];

  float* w = (float*)d_ws;
  size_t need = 0;
  auto alloc = [&](size_t nfl){ nfl = (nfl + 3) & ~(size_t)3; float* r = w + need; need += nfl; return r; };
  p.A_K  = alloc((size_t)NTOT*DD);
  p.A_V  = alloc((size_t)NTOT*DD);
  p.Wg1  = alloc(2*DD);
  p.c1   = alloc(DD);
  p.Wf2T = alloc(DD*DD);
  p.slots_g = alloc(320*128);
  p.qw_g    = alloc(320*128);
  p.qb_g    = alloc(320);
  p.spss_g  = alloc(320*4);
  p.hpart_g = alloc((size_t)NB*7*8*136);
  p.a_g     = alloc((size_t)8*8*NT);
  p.WQp  = (float4*)alloc(4096*4);
  p.f2P  = (float4*)alloc(4096*4);
  p.f2TP = (float4*)alloc(4096*4);
  p.finP = (float4*)alloc(4096*4);
  p.gihP = (float4*)alloc(12288*4);
  p.ghhP = (float4*)alloc(12288*4);
  p.w1P  = (float4*)alloc(16384*4);
  p.w2P  = (float4*)alloc(16384*4);
  p.xnh  = (ushort*)alloc((size_t)NTOT*DIN/2);
  p.xnl  = (ushort*)alloc((size_t)NTOT*DIN/2);
  p.hh   = (ushort*)alloc((size_t)NTOT*DIN/2);
  p.hl   = (ushort*)alloc((size_t)NTOT*DIN/2);
  p.W1Th = (ushort*)alloc((size_t)DIN*DIN/2);
  p.W1Tl = (ushort*)alloc((size_t)DIN*DIN/2);
  p.W2Th = (ushort*)alloc((size_t)DD*DIN/2);
  p.W2Tl = (ushort*)alloc((size_t)DD*DIN/2);
  p.WKfTh = (ushort*)alloc(DD*DD/2);
  p.WKfTl = (ushort*)alloc(DD*DD/2);
  p.WVfTh = (ushort*)alloc(DD*DD/2);
  p.WVfTl = (ushort*)alloc(DD*DD/2);
  p.out = (float*)d_out;
  if (ws_size < need*sizeof(float)){
    fprintf(stderr, "kernel_launch: ws too small (%zu < %zu)\n", ws_size, need*sizeof(float));
    return;
  }

  prep_weights<<<dim3(DD), dim3(128), 0, stream>>>(p);
  prep_pack<<<dim3(288), dim3(256), 0, stream>>>(p);
  transpose_both<<<dim3(168), dim3(256), 0, stream>>>(p);
  ln1_init<<<dim3(4730), dim3(256), 0, stream>>>(p);
  gemm1_128<<<dim3(832), dim3(256), 0, stream>>>(p);
  gemm2_fused<<<dim3((NTOT+31)/32), dim3(256), 0, stream>>>(p);

  for (int t = 0; t < 3; t++){
    kA<0><<<dim3(NB*7), dim3(256), 0, stream>>>(p);
    kB<0><<<dim3(320), dim3(256), 0, stream>>>(p);
  }
  kA<1><<<dim3(NB*7), dim3(256), 0, stream>>>(p);
  kB<1><<<dim3(320), dim3(256), 0, stream>>>(p);
}